// Round 6
// baseline (4501.395 us; speedup 1.0000x reference)
//
#include <hip/hip_runtime.h>
#include <math.h>

// ---------------------------------------------------------------------------
// TDS decoder R6: persistent kernel, 256 blocks x 1024 threads (R4 shape)
// with seqlock-style single-writer publish (R5 handshake, full grid).
// Per block per step: one 256B region = 41 logit/S partials + hp + 6 gh rows,
// tag in EVERY 64B sector (lanes 15/31/47/63), published by one predicated
// RELEASE store (vmcnt drain => tag fresh implies sector data at MALL).
// Waves 0-7 poll+gather 32 regions each (data+tag in one load); wave0 decides
// and releases best via LDS. Waves 8-15 run the GRU concurrently, polling
// their 3 gh sector tags. No atomics, no counters, no zeroing, no init kernel
// (0xAA poison never equals a tag value).
// Region layout (64 floats): p[0..14]->0..14, p[15..29]->16..30,
// p[30..40]->32..42 (S=p[40]@42), hp@43, gh[0..5]@48..53, tags@15/31/47/63.
// ---------------------------------------------------------------------------

#define NV      40
#define TENC    8192
#define MAXLEN  200
#define EOS_IDX 38
#define NB      256
#define NT      1024
#define NW      16
#define ROWS    32                    /* K rows per block (2 per wave)      */
#define RS      64                    /* region stride: 64 floats = 256 B   */
#define SLOTF   (NB * RS)             /* 16384 floats per rotation slot     */
#define SCALE   0.04419417382415922f  /* 1/sqrt(512) */

#define WS_REG  0                     /* float[3][SLOTF]                    */
#define WS_GI   (3 * SLOTF)           /* 49152: float[40*1536]              */

__device__ __forceinline__ int ld_ai(const float* p) {
  return __hip_atomic_load((const int*)p, __ATOMIC_RELAXED,
                           __HIP_MEMORY_SCOPE_AGENT);
}
__device__ __forceinline__ float ld_af(const float* p) {
  return __hip_atomic_load(p, __ATOMIC_RELAXED, __HIP_MEMORY_SCOPE_AGENT);
}
__device__ __forceinline__ void st_af(float* p, float v) {
  __hip_atomic_store(p, v, __ATOMIC_RELAXED, __HIP_MEMORY_SCOPE_AGENT);
}
__device__ __forceinline__ void st_tag_rel(float* p, int v) {
  __hip_atomic_store((int*)p, v, __ATOMIC_RELEASE, __HIP_MEMORY_SCOPE_AGENT);
}
__device__ __forceinline__ int ld_lds_acq(int* p) {
  return __hip_atomic_load(p, __ATOMIC_ACQUIRE, __HIP_MEMORY_SCOPE_WORKGROUP);
}
__device__ __forceinline__ void st_lds_rel(int* p, int v) {
  __hip_atomic_store(p, v, __ATOMIC_RELEASE, __HIP_MEMORY_SCOPE_WORKGROUP);
}
__device__ __forceinline__ void lds_add_rel(int* p) {
  __hip_atomic_fetch_add(p, 1, __ATOMIC_RELEASE, __HIP_MEMORY_SCOPE_WORKGROUP);
}

__device__ __forceinline__ float wred(float s) {
#pragma unroll
  for (int o = 32; o > 0; o >>= 1) s += __shfl_xor(s, o, 64);
  return s;
}
__device__ __forceinline__ float dot8(float4 a0, float4 a1, float4 b0,
                                      float4 b1) {
  return a0.x * b0.x + a0.y * b0.y + a0.z * b0.z + a0.w * b0.w +
         a1.x * b1.x + a1.y * b1.y + a1.z * b1.z + a1.w * b1.w;
}
__device__ __forceinline__ float wdot512(const float* __restrict__ a,
                                         const float* __restrict__ b) {
  const int l = threadIdx.x & 63;
  const float4 a0 = ((const float4*)a)[l];
  const float4 a1 = ((const float4*)a)[l + 64];
  const float4 b0 = ((const float4*)b)[l];
  const float4 b1 = ((const float4*)b)[l + 64];
  return wred(dot8(a0, a1, b0, b1));
}

__global__ void __launch_bounds__(NT, 4) dec_main(
    const float* __restrict__ enc, const float* __restrict__ hidden,
    const float* __restrict__ embed, const float* __restrict__ w_ih,
    const float* __restrict__ w_hh, const float* __restrict__ b_ih,
    const float* __restrict__ b_hh, const float* __restrict__ w_out,
    const float* __restrict__ b_out, float* __restrict__ o,
    float* __restrict__ ws) {
  const int b = blockIdx.x, tid = threadIdx.x;
  const int wave = tid >> 6, lane = tid & 63;
  const int r0 = b * ROWS;
  // packed-position map (lanes 15/31/47/63 are tags)
  const int pos = (lane <= 40) ? lane + (lane >= 15) + (lane >= 30) : lane;

  __shared__ __align__(16) float h_lds[512];
  __shared__ float pw_lds[NW * 64];   // dot-phase fold partials
  __shared__ float pwg_lds[8 * 64];   // gather-wave partial colsums
  __shared__ float hp_lds[NV];
  __shared__ float stage_gh[6];
  __shared__ float stage_hp[1];
  __shared__ float sc_lds[1];
  __shared__ int gcnt;                // monotonic gather counter
  __shared__ int bf_lds;              // (t<<6)|best

  // ----------------- prologue -----------------
  if (tid < 512) h_lds[tid] = hidden[tid];
  if (tid == 0) { gcnt = 0; bf_lds = -1; }

  // gi_all[v][j] = W_ih[j].embed[v] + b_ih[j]  (240 dots per block)
  for (int u = wave; u < 240; u += NW) {
    const int gl = b * 240 + u;
    const int v = gl / 1536, j = gl - v * 1536;
    const float d = wdot512(w_ih + (size_t)j * 512, embed + (size_t)v * 512);
    if (lane == 0) st_af(&ws[WS_GI + (size_t)v * 1536 + j], d + b_ih[j]);
  }
  // gh(h0): 6 rows (waves 0-5) -> stage
  if (wave < 6) {
    const int j = b * 6 + wave;
    const float d = wdot512(w_hh + (size_t)j * 512, hidden);
    if (lane == 0) stage_gh[wave] = d + b_hh[j];
  }
  __syncthreads();  // drains all waves' gi stores (vmcnt0 before s_barrier)
  if (wave == 0) {  // publish prologue region: slot 2, tag 0 (gh only)
    float* outp = ws + WS_REG + 2 * SLOTF + b * RS;
    if (lane >= 48 && lane < 54) st_af(outp + lane, stage_gh[lane - 48]);
    if ((lane & 15) == 15) st_tag_rel(outp + lane, 0);
  }

  // --- register-resident K rows and M columns ---
  const float* k0p = enc + (size_t)(r0 + 2 * wave) * 1024;
  const float4 k0a = ((const float4*)k0p)[lane];
  const float4 k0b = ((const float4*)k0p)[lane + 64];
  const float4 k1a = ((const float4*)(k0p + 1024))[lane];
  const float4 k1b = ((const float4*)(k0p + 1024))[lane + 64];
  float Mr0 = (lane == 40) ? 1.0f : 0.0f, Mr1 = Mr0;
  {
    const float* v0p = k0p + 512;
    const float4 va0 = ((const float4*)v0p)[lane];
    const float4 va1 = ((const float4*)v0p)[lane + 64];
    const float4 vb0 = ((const float4*)(v0p + 1024))[lane];
    const float4 vb1 = ((const float4*)(v0p + 1024))[lane + 64];
    for (int v = 0; v < NV; ++v) {
      const float* wp = w_out + (size_t)v * 1024;
      const float4 w0 = ((const float4*)wp)[lane];
      const float4 w1 = ((const float4*)wp)[lane + 64];
      const float sa = wred(dot8(va0, va1, w0, w1));
      const float sb = wred(dot8(vb0, vb1, w0, w1));
      if (lane == v) { Mr0 = sa; Mr1 = sb; }
    }
  }
  // aux row regs: waves1-6 -> W_hh row; wave7 -> W_out hp row (blocks 1..40)
  float4 xa0 = {0, 0, 0, 0}, xa1 = {0, 0, 0, 0};
  float xb = 0.0f;
  if (wave >= 1 && wave <= 6) {
    const int j = b * 6 + (wave - 1);
    const float* wp = w_hh + (size_t)j * 512;
    xa0 = ((const float4*)wp)[lane];
    xa1 = ((const float4*)wp)[lane + 64];
    xb = b_hh[j];
  } else if (wave == 7 && b >= 1 && b <= NV) {
    const float* wp = w_out + (size_t)(b - 1) * 1024 + 512;
    xa0 = ((const float4*)wp)[lane];
    xa1 = ((const float4*)wp)[lane + 64];
    xb = b_out[b - 1];
  }
  // GRU source offsets (3 gh components from 3 regions)
  int of0 = 0, tg0 = 0, of1 = 0, tg1 = 0, of2 = 0, tg2 = 0;
  if (tid >= 512) {
    const int j = tid - 512;
    const int rA = j / 6, rB = (j + 512) / 6, rC = (j + 1024) / 6;
    of0 = rA * RS + 48 + j % 6;          tg0 = rA * RS + 63;
    of1 = rB * RS + 48 + (j + 512) % 6;  tg1 = rB * RS + 63;
    of2 = rC * RS + 48 + (j + 1024) % 6; tg2 = rC * RS + 63;
  }

  // ----------------- main loop -----------------
  int eos_reg = -1;            // block0/wave0/lane0 only
  float p0 = 0.0f, p1 = 0.0f;  // this wave's unnormalized attention weights
  float* attn = o + (size_t)MAXLEN * NV + 1;

  for (int t = 0; t <= MAXLEN; ++t) {
    float* sbase = ws + WS_REG + ((t + 2) % 3) * SLOTF;  // tag == t when fresh

    if (wave < 8) {
      // ---- combined poll+gather: 32 regions per wave, sticky ----
      unsigned undone = 0xFFFFFFFFu;
      float cs = 0.0f, hpv = 0.0f;
      bool hpown = false;
      while (undone) {
        unsigned m = undone;
        while (m) {
          const int r = __ffs(m) - 1;
          m &= m - 1;
          const int g = (wave << 5) + r;
          const float x = ld_af(sbase + g * RS + lane);
          const int t15 = __float_as_int(__shfl(x, 15));
          const int t31 = __float_as_int(__shfl(x, 31));
          const int t47 = __float_as_int(__shfl(x, 47));
          const int t63 = __float_as_int(__shfl(x, 63));
          if (t15 == t && t31 == t && t47 == t && t63 == t) {
            if (t > 0) {
              const float p = __shfl(x, pos);
              if (lane <= 40) cs += p;
              const float h43 = __shfl(x, 43);
              if (g >= 1 && g <= NV && lane == g - 1) { hpv = h43; hpown = true; }
            }
            undone &= ~(1u << r);
          }
        }
        if (undone) __builtin_amdgcn_s_sleep(1);
      }
      pwg_lds[wave * 64 + lane] = cs;
      if (hpown) hp_lds[lane] = hpv;
      if (lane == 0) lds_add_rel(&gcnt);
      if (wave == 0) {
        while (ld_lds_acq(&gcnt) < 8 * (t + 1)) __builtin_amdgcn_s_sleep(1);
        if (t > 0) {
          float cs8 = 0.0f;
#pragma unroll
          for (int w2 = 0; w2 < 8; ++w2) cs8 += pwg_lds[w2 * 64 + lane];
          const float S = __shfl(cs8, 40);
          const float hp = (lane < NV) ? hp_lds[lane] : 0.0f;
          const float ov = cs8 * (1.0f / S) + hp;
          unsigned long long key = 0ull;
          if (lane < NV) {
            unsigned u = __float_as_uint(ov);
            u = (u & 0x80000000u) ? ~u : (u | 0x80000000u);
            key = ((unsigned long long)u << 32) | (unsigned)(~lane);
          }
#pragma unroll
          for (int mm = 32; mm > 0; mm >>= 1) {
            const unsigned long long k2 = __shfl_xor(key, mm, 64);
            if (k2 > key) key = k2;
          }
          const int best = (int)(~(unsigned)key);
          if (lane == 0) sc_lds[0] = S;
          if (b == 0 && lane < NV) o[(size_t)(t - 1) * NV + lane] = ov;
          if (b == 0 && lane == 0) {
            if (best == EOS_IDX && eos_reg < 0) eos_reg = t - 1;
            if (t == MAXLEN)
              o[(size_t)MAXLEN * NV] =
                  (eos_reg < 0) ? (float)MAXLEN : (float)eos_reg;
          }
          if (lane == 0) st_lds_rel(&bf_lds, (t << 6) | best);
        } else if (lane == 0) {
          st_lds_rel(&bf_lds, EOS_IDX);  // (0<<6)|EOS
        }
      }
    } else if (t < MAXLEN) {
      // ---- GRU waves 8-15: self-poll 3 gh sector tags ----
      const int j = tid - 512;
      float ghr = 0.0f, ghz = 0.0f, ghn = 0.0f;
      bool d0 = false, d1 = false, d2 = false;
      for (;;) {
        if (!d0 && ld_ai(sbase + tg0) == t) { ghr = ld_af(sbase + of0); d0 = true; }
        if (!d1 && ld_ai(sbase + tg1) == t) { ghz = ld_af(sbase + of1); d1 = true; }
        if (!d2 && ld_ai(sbase + tg2) == t) { ghn = ld_af(sbase + of2); d2 = true; }
        if (d0 && d1 && d2) break;
        __builtin_amdgcn_s_sleep(1);
      }
      int bf;
      while (((bf = ld_lds_acq(&bf_lds)) >> 6) < t) __builtin_amdgcn_s_sleep(1);
      const float* gi = ws + WS_GI + (size_t)(bf & 63) * 1536;
      const float gir = gi[j], giz = gi[j + 512], gin = gi[j + 1024];
      const float r = 1.0f / (1.0f + expf(-(gir + ghr)));
      const float z = 1.0f / (1.0f + expf(-(giz + ghz)));
      const float n = tanhf(gin + r * ghn);
      h_lds[j] = (1.0f - z) * n + z * h_lds[j];
    }
    __syncthreads();  // barrier A: h_t, sc_lds ready

    if (t > 0 && lane < 2)  // previous step's normalized attention weights
      attn[(size_t)(t - 1) * TENC + r0 + 2 * wave + lane] =
          (lane ? p1 : p0) * (1.0f / sc_lds[0]);
    if (t == MAXLEN) break;

    // ---- dots: 2 K-dots + fold partial (regs); aux row (regs) ----
    {
      const float4 hh0 = ((const float4*)h_lds)[lane];
      const float4 hh1 = ((const float4*)h_lds)[lane + 64];
      const float d0 = wred(dot8(k0a, k0b, hh0, hh1));
      const float d1 = wred(dot8(k1a, k1b, hh0, hh1));
      p0 = expf(d0 * SCALE);
      p1 = expf(d1 * SCALE);
      if (lane <= 40) pw_lds[wave * 64 + lane] = p0 * Mr0 + p1 * Mr1;
      if (wave >= 1 && wave <= 6) {  // gh_t row for step t+1
        const float d = wred(dot8(xa0, xa1, hh0, hh1));
        if (lane == 0) stage_gh[wave - 1] = d + xb;
      } else if (wave == 7 && b >= 1 && b <= NV) {  // hp row
        const float d = wred(dot8(xa0, xa1, hh0, hh1));
        if (lane == 0) stage_hp[0] = d + xb;
      }
    }
    __syncthreads();  // barrier C: pw/stage complete

    // ---- wave0: pack region, publish with per-sector release tags ----
    if (wave == 0) {
      float* outp = ws + WS_REG + (t % 3) * SLOTF + b * RS;
      float red = 0.0f;
      if (lane <= 40) {
#pragma unroll
        for (int w2 = 0; w2 < NW; ++w2) red += pw_lds[w2 * 64 + lane];
        st_af(outp + pos, red);
      }
      if (lane == 41)
        st_af(outp + 43, (b >= 1 && b <= NV) ? stage_hp[0] : 0.0f);
      if (lane >= 48 && lane < 54) st_af(outp + lane, stage_gh[lane - 48]);
      if ((lane & 15) == 15) st_tag_rel(outp + lane, t + 1);
    }
  }
}

extern "C" void kernel_launch(void* const* d_in, const int* in_sizes, int n_in,
                              void* d_out, int out_size, void* d_ws,
                              size_t ws_size, hipStream_t stream) {
  const float* enc    = (const float*)d_in[0];
  const float* hidden = (const float*)d_in[1];
  const float* embed  = (const float*)d_in[2];
  const float* w_ih   = (const float*)d_in[3];
  const float* w_hh   = (const float*)d_in[4];
  const float* b_ih   = (const float*)d_in[5];
  const float* b_hh   = (const float*)d_in[6];
  const float* w_out  = (const float*)d_in[7];
  const float* b_out  = (const float*)d_in[8];
  float* out = (float*)d_out;
  float* ws  = (float*)d_ws;

  dec_main<<<dim3(NB), dim3(NT), 0, stream>>>(enc, hidden, embed, w_ih, w_hh,
                                              b_ih, b_hh, w_out, b_out, out,
                                              ws);
}

// Round 7
// 2673.532 us; speedup vs baseline: 1.6837x; 1.6837x over previous
//
#include <hip/hip_runtime.h>
#include <math.h>

// ---------------------------------------------------------------------------
// TDS decoder R7: persistent kernel, 256 blocks x 1024 threads.
// Seqlock single-writer publish (1 release tag store into a DENSE tag array)
// + lane-parallel tag poll + pipelined region gather (no shuffles).
//  - Region b (64 floats, 256 B): [0..40]=logit/S partials, [41]=hp,
//    [42..47]=gh rows b*6..b*6+5. Tags: int[3][256] dense array.
//  - Waves 0-7: poll own 32 tags (1 load + ballot), gather 32 regions with
//    independent pipelined loads, partial-sum into LDS; wave0 reduces,
//    decides (packed argmax), releases best via LDS.
//  - Waves 8-15: poll their 3 gh tags, load gh immediately, wait best, GRU.
//  - t=0: wave0 polls all 256 prologue tags (gi table readiness).
// No atomics, no counters, no zeroing, no init kernel (0xAA != any tag).
// ---------------------------------------------------------------------------

#define NV      40
#define TENC    8192
#define MAXLEN  200
#define EOS_IDX 38
#define NB      256
#define NT      1024
#define NW      16
#define ROWS    32                    /* K rows per block (2 per wave)      */
#define RS      64                    /* region stride: 64 floats = 256 B   */
#define SLOTF   (NB * RS)             /* 16384 floats per rotation slot     */
#define SCALE   0.04419417382415922f  /* 1/sqrt(512) */

#define WS_TAG  0                     /* int[3][256]                        */
#define WS_REG  768                   /* float[3][SLOTF]                    */
#define WS_GI   (768 + 3 * SLOTF)     /* 49920: float[40*1536]              */

__device__ __forceinline__ int ld_tag(const int* p) {
  return __hip_atomic_load(p, __ATOMIC_RELAXED, __HIP_MEMORY_SCOPE_AGENT);
}
__device__ __forceinline__ float ld_af(const float* p) {
  return __hip_atomic_load(p, __ATOMIC_RELAXED, __HIP_MEMORY_SCOPE_AGENT);
}
__device__ __forceinline__ void st_af(float* p, float v) {
  __hip_atomic_store(p, v, __ATOMIC_RELAXED, __HIP_MEMORY_SCOPE_AGENT);
}
__device__ __forceinline__ void st_tag_rel(int* p, int v) {
  __hip_atomic_store(p, v, __ATOMIC_RELEASE, __HIP_MEMORY_SCOPE_AGENT);
}
__device__ __forceinline__ int ld_lds_acq(int* p) {
  return __hip_atomic_load(p, __ATOMIC_ACQUIRE, __HIP_MEMORY_SCOPE_WORKGROUP);
}
__device__ __forceinline__ void st_lds_rel(int* p, int v) {
  __hip_atomic_store(p, v, __ATOMIC_RELEASE, __HIP_MEMORY_SCOPE_WORKGROUP);
}
__device__ __forceinline__ void lds_add_rel(int* p) {
  __hip_atomic_fetch_add(p, 1, __ATOMIC_RELEASE, __HIP_MEMORY_SCOPE_WORKGROUP);
}

__device__ __forceinline__ float wred(float s) {
#pragma unroll
  for (int o = 32; o > 0; o >>= 1) s += __shfl_xor(s, o, 64);
  return s;
}
__device__ __forceinline__ float dot8(float4 a0, float4 a1, float4 b0,
                                      float4 b1) {
  return a0.x * b0.x + a0.y * b0.y + a0.z * b0.z + a0.w * b0.w +
         a1.x * b1.x + a1.y * b1.y + a1.z * b1.z + a1.w * b1.w;
}
__device__ __forceinline__ float wdot512(const float* __restrict__ a,
                                         const float* __restrict__ b) {
  const int l = threadIdx.x & 63;
  const float4 a0 = ((const float4*)a)[l];
  const float4 a1 = ((const float4*)a)[l + 64];
  const float4 b0 = ((const float4*)b)[l];
  const float4 b1 = ((const float4*)b)[l + 64];
  return wred(dot8(a0, a1, b0, b1));
}

__global__ void __launch_bounds__(NT, 4) dec_main(
    const float* __restrict__ enc, const float* __restrict__ hidden,
    const float* __restrict__ embed, const float* __restrict__ w_ih,
    const float* __restrict__ w_hh, const float* __restrict__ b_ih,
    const float* __restrict__ b_hh, const float* __restrict__ w_out,
    const float* __restrict__ b_out, float* __restrict__ o,
    float* __restrict__ ws) {
  const int b = blockIdx.x, tid = threadIdx.x;
  const int wave = tid >> 6, lane = tid & 63;
  const int r0 = b * ROWS;
  int* wsi = (int*)ws;

  __shared__ __align__(16) float h_lds[512];
  __shared__ float pw_lds[NW * 64];   // dot-phase fold partials
  __shared__ float pwg_lds[8 * 64];   // gather-wave partial colsums
  __shared__ float hp_lds[NV];
  __shared__ float stage_gh[6];
  __shared__ float stage_hp[1];
  __shared__ float sc_lds[1];
  __shared__ int gcnt;                // monotonic gather counter
  __shared__ int bf_lds;              // (t<<6)|best

  // ----------------- prologue -----------------
  if (tid < 512) h_lds[tid] = hidden[tid];
  if (tid == 0) { gcnt = 0; bf_lds = -1; stage_hp[0] = 0.0f; }

  // gi_all[v][j] = W_ih[j].embed[v] + b_ih[j]  (240 dots per block)
  for (int u = wave; u < 240; u += NW) {
    const int gl = b * 240 + u;
    const int v = gl / 1536, j = gl - v * 1536;
    const float d = wdot512(w_ih + (size_t)j * 512, embed + (size_t)v * 512);
    if (lane == 0) st_af(&ws[WS_GI + (size_t)v * 1536 + j], d + b_ih[j]);
  }
  // gh(h0): 6 rows (waves 0-5) -> stage
  if (wave < 6) {
    const int j = b * 6 + wave;
    const float d = wdot512(w_hh + (size_t)j * 512, hidden);
    if (lane == 0) stage_gh[wave] = d + b_hh[j];
  }
  __syncthreads();  // drains ALL waves' gi stores (vmcnt0 before s_barrier)
  if (wave == 0) {  // publish prologue region into slot 2, tag 0
    float* outp = ws + WS_REG + 2 * SLOTF + b * RS;
    if (lane >= 42 && lane < 48) st_af(outp + lane, stage_gh[lane - 42]);
    if (lane == 0) st_tag_rel(wsi + WS_TAG + 2 * 256 + b, 0);
  }

  // --- register-resident K rows and M columns ---
  const float* k0p = enc + (size_t)(r0 + 2 * wave) * 1024;
  const float4 k0a = ((const float4*)k0p)[lane];
  const float4 k0b = ((const float4*)k0p)[lane + 64];
  const float4 k1a = ((const float4*)(k0p + 1024))[lane];
  const float4 k1b = ((const float4*)(k0p + 1024))[lane + 64];
  float Mr0 = (lane == 40) ? 1.0f : 0.0f, Mr1 = Mr0;
  {
    const float* v0p = k0p + 512;
    const float4 va0 = ((const float4*)v0p)[lane];
    const float4 va1 = ((const float4*)v0p)[lane + 64];
    const float4 vb0 = ((const float4*)(v0p + 1024))[lane];
    const float4 vb1 = ((const float4*)(v0p + 1024))[lane + 64];
    for (int v = 0; v < NV; ++v) {
      const float* wp = w_out + (size_t)v * 1024;
      const float4 w0 = ((const float4*)wp)[lane];
      const float4 w1 = ((const float4*)wp)[lane + 64];
      const float sa = wred(dot8(va0, va1, w0, w1));
      const float sb = wred(dot8(vb0, vb1, w0, w1));
      if (lane == v) { Mr0 = sa; Mr1 = sb; }
    }
  }
  // aux row regs: waves 1-6 -> W_hh row; wave 7 -> W_out hp row (blocks 1..40)
  float4 xa0 = {0, 0, 0, 0}, xa1 = {0, 0, 0, 0};
  float xb = 0.0f;
  if (wave >= 1 && wave <= 6) {
    const int j = b * 6 + (wave - 1);
    const float* wp = w_hh + (size_t)j * 512;
    xa0 = ((const float4*)wp)[lane];
    xa1 = ((const float4*)wp)[lane + 64];
    xb = b_hh[j];
  } else if (wave == 7 && b >= 1 && b <= NV) {
    const float* wp = w_out + (size_t)(b - 1) * 1024 + 512;
    xa0 = ((const float4*)wp)[lane];
    xa1 = ((const float4*)wp)[lane + 64];
    xb = b_out[b - 1];
  }
  // GRU source mapping: thread j reads gh rows j, j+512, j+1024
  int rA = 0, rB = 0, rC = 0, oA = 0, oB = 0, oC = 0;
  if (tid >= 512) {
    const int j = tid - 512;
    rA = j / 6;          oA = rA * RS + 42 + (j % 6);
    rB = (j + 512) / 6;  oB = rB * RS + 42 + ((j + 512) % 6);
    rC = (j + 1024) / 6; oC = rC * RS + 42 + ((j + 1024) % 6);
  }

  // ----------------- main loop -----------------
  int eos_reg = -1;            // block0/wave0/lane0 only
  float p0 = 0.0f, p1 = 0.0f;  // this wave's unnormalized attention weights
  float* attn = o + (size_t)MAXLEN * NV + 1;

  for (int t = 0; t <= MAXLEN; ++t) {
    const int s = (t + 2) % 3;                 // slot holding step-(t-1) data
    const float* rb = ws + WS_REG + s * SLOTF;
    const int* tg = wsi + WS_TAG + s * 256;

    if (wave < 8) {
      if (t > 0) {
        // ---- lane-parallel poll of this wave's 32 tags ----
        {
          bool ok = (lane >= 32);
          const int* tp = tg + wave * 32 + lane;
          for (;;) {
            if (!ok) ok = (ld_tag(tp) == t);
            if (__ballot(!ok) == 0ull) break;
            __builtin_amdgcn_s_sleep(1);
          }
        }
        // ---- pipelined gather: 32 independent region loads ----
        const float* rbl = rb + (wave * 32) * RS + lane;
        float c0 = 0, c1 = 0, c2 = 0, c3 = 0;
#pragma unroll
        for (int q = 0; q < 8; ++q) {
          const float x0 = ld_af(rbl + (4 * q + 0) * RS);
          const float x1 = ld_af(rbl + (4 * q + 1) * RS);
          const float x2 = ld_af(rbl + (4 * q + 2) * RS);
          const float x3 = ld_af(rbl + (4 * q + 3) * RS);
          c0 += x0; c1 += x1; c2 += x2; c3 += x3;
          if (wave < 2 && lane == 41) {  // hp of region g lives in lane 41
            const int g0 = wave * 32 + 4 * q;
            if ((unsigned)(g0 - 1) < NV) hp_lds[g0 - 1] = x0;
            if ((unsigned)(g0 + 0) < NV) hp_lds[g0 + 0] = x1;
            if ((unsigned)(g0 + 1) < NV) hp_lds[g0 + 1] = x2;
            if ((unsigned)(g0 + 2) < NV) hp_lds[g0 + 2] = x3;
          }
        }
        pwg_lds[wave * 64 + lane] = (c0 + c1) + (c2 + c3);
        if (lane == 0) lds_add_rel(&gcnt);
        if (wave == 0) {
          while (ld_lds_acq(&gcnt) < 8 * t) __builtin_amdgcn_s_sleep(1);
          float cs8 = 0.0f;
#pragma unroll
          for (int w2 = 0; w2 < 8; ++w2) cs8 += pwg_lds[w2 * 64 + lane];
          const float S = __shfl(cs8, 40, 64);
          const float hp = (lane < NV) ? hp_lds[lane] : 0.0f;
          const float ov = cs8 * (1.0f / S) + hp;
          unsigned long long key = 0ull;
          if (lane < NV) {
            unsigned u = __float_as_uint(ov);
            u = (u & 0x80000000u) ? ~u : (u | 0x80000000u);
            key = ((unsigned long long)u << 32) | (unsigned)(~lane);
          }
#pragma unroll
          for (int mm = 32; mm > 0; mm >>= 1) {
            const unsigned long long k2 = __shfl_xor(key, mm, 64);
            if (k2 > key) key = k2;
          }
          const int best = (int)(~(unsigned)key);
          if (lane == 0) sc_lds[0] = S;
          if (b == 0 && lane < NV) o[(size_t)(t - 1) * NV + lane] = ov;
          if (b == 0 && lane == 0) {
            if (best == EOS_IDX && eos_reg < 0) eos_reg = t - 1;
            if (t == MAXLEN)
              o[(size_t)MAXLEN * NV] =
                  (eos_reg < 0) ? (float)MAXLEN : (float)eos_reg;
          }
          if (lane == 0) st_lds_rel(&bf_lds, (t << 6) | best);
        }
      } else if (wave == 0) {
        // t==0: full poll of all 256 prologue tags (gi-table readiness)
        bool ok = false;
        const int* tp = tg + lane;
        for (;;) {
          if (!ok)
            ok = (ld_tag(tp) == 0 && ld_tag(tp + 64) == 0 &&
                  ld_tag(tp + 128) == 0 && ld_tag(tp + 192) == 0);
          if (__ballot(!ok) == 0ull) break;
          __builtin_amdgcn_s_sleep(1);
        }
        if (lane == 0) st_lds_rel(&bf_lds, EOS_IDX);  // (0<<6)|EOS
      }
    } else if (t < MAXLEN) {
      // ---- GRU waves 8-15: poll own 3 tags, load gh immediately ----
      const int j = tid - 512;
      float ghr = 0.0f, ghz = 0.0f, ghn = 0.0f;
      bool d0 = false, d1 = false, d2 = false;
      for (;;) {
        if (!d0 && ld_tag(tg + rA) == t) { ghr = ld_af(rb + oA); d0 = true; }
        if (!d1 && ld_tag(tg + rB) == t) { ghz = ld_af(rb + oB); d1 = true; }
        if (!d2 && ld_tag(tg + rC) == t) { ghn = ld_af(rb + oC); d2 = true; }
        if (__ballot(!(d0 && d1 && d2)) == 0ull) break;
        __builtin_amdgcn_s_sleep(1);
      }
      int bf;
      while (((bf = ld_lds_acq(&bf_lds)) >> 6) < t) __builtin_amdgcn_s_sleep(1);
      const float* gi = ws + WS_GI + (size_t)(bf & 63) * 1536;
      const float gir = gi[j], giz = gi[j + 512], gin = gi[j + 1024];
      const float r = 1.0f / (1.0f + expf(-(gir + ghr)));
      const float z = 1.0f / (1.0f + expf(-(giz + ghz)));
      const float n = tanhf(gin + r * ghn);
      h_lds[j] = (1.0f - z) * n + z * h_lds[j];
    }
    __syncthreads();  // barrier A: h_t, sc_lds ready

    if (t > 0 && lane < 2)  // previous step's normalized attention weights
      attn[(size_t)(t - 1) * TENC + r0 + 2 * wave + lane] =
          (lane ? p1 : p0) * (1.0f / sc_lds[0]);
    if (t == MAXLEN) break;

    // ---- dots: 2 K-dots + fold partial (regs); aux row (regs) ----
    {
      const float4 hh0 = ((const float4*)h_lds)[lane];
      const float4 hh1 = ((const float4*)h_lds)[lane + 64];
      const float d0 = wred(dot8(k0a, k0b, hh0, hh1));
      const float d1 = wred(dot8(k1a, k1b, hh0, hh1));
      p0 = expf(d0 * SCALE);
      p1 = expf(d1 * SCALE);
      if (lane <= 40) pw_lds[wave * 64 + lane] = p0 * Mr0 + p1 * Mr1;
      if (wave >= 1 && wave <= 6) {  // gh_t row for step t+1
        const float d = wred(dot8(xa0, xa1, hh0, hh1));
        if (lane == 0) stage_gh[wave - 1] = d + xb;
      } else if (wave == 7 && b >= 1 && b <= NV) {  // hp row
        const float d = wred(dot8(xa0, xa1, hh0, hh1));
        if (lane == 0) stage_hp[0] = d + xb;
      }
    }
    __syncthreads();  // barrier C: pw/stage complete

    // ---- wave0: pack region, publish, single release tag store ----
    if (wave == 0) {
      float* outp = ws + WS_REG + (t % 3) * SLOTF + b * RS;
      float val = 0.0f;
      if (lane <= 40) {
        float red = 0.0f;
#pragma unroll
        for (int w2 = 0; w2 < NW; ++w2) red += pw_lds[w2 * 64 + lane];
        val = red;
      } else if (lane == 41) {
        val = (b >= 1 && b <= NV) ? stage_hp[0] : 0.0f;
      } else if (lane < 48) {
        val = stage_gh[lane - 42];
      }
      if (lane < 48) st_af(outp + lane, val);
      if (lane == 0) st_tag_rel(wsi + WS_TAG + (t % 3) * 256 + b, t + 1);
    }
  }
}

extern "C" void kernel_launch(void* const* d_in, const int* in_sizes, int n_in,
                              void* d_out, int out_size, void* d_ws,
                              size_t ws_size, hipStream_t stream) {
  const float* enc    = (const float*)d_in[0];
  const float* hidden = (const float*)d_in[1];
  const float* embed  = (const float*)d_in[2];
  const float* w_ih   = (const float*)d_in[3];
  const float* w_hh   = (const float*)d_in[4];
  const float* b_ih   = (const float*)d_in[5];
  const float* b_hh   = (const float*)d_in[6];
  const float* w_out  = (const float*)d_in[7];
  const float* b_out  = (const float*)d_in[8];
  float* out = (float*)d_out;
  float* ws  = (float*)d_ws;

  dec_main<<<dim3(NB), dim3(NT), 0, stream>>>(enc, hidden, embed, w_ih, w_hh,
                                              b_ih, b_hh, w_out, b_out, out,
                                              ws);
}

// Round 8
// 1876.858 us; speedup vs baseline: 2.3984x; 1.4245x over previous
//
#include <hip/hip_runtime.h>
#include <math.h>

// ---------------------------------------------------------------------------
// TDS decoder R8: persistent kernel, 256 blocks x 1024 threads.
// Topology = R4 (atomic pre-reduction into 64 group regions, ONE poller wave
// per block, LDS fan-out) with R4's two warts fixed:
//  - publish: 41 relaxed atomicAdds -> vmcnt drain -> ONE release tag store
//    into a dense int[3][256] tag array (no counter RMW, 16-line poll).
//  - gather: waves 0-7 load 8 group regions each after LDS 'go' (overlaps
//    GRU gh loads); wave0 reduces, decides, releases best via LDS.
// gh (1536 rows) distributed 6/block into dense gh[3][1536]; hp distributed
// blocks 1..40. Group accumulators zeroed in-loop by wave15 of blocks 0-63
// (slot provably consumed); slots 0/1 zeroed in prologue. No init kernel.
// ---------------------------------------------------------------------------

#define NV      40
#define TENC    8192
#define MAXLEN  200
#define EOS_IDX 38
#define NB      256
#define NT      1024
#define NW      16
#define ROWS    32                    /* K rows per block (2 per wave)      */
#define NG      64                    /* groups; 4 blocks add per group     */
#define SCALE   0.04419417382415922f  /* 1/sqrt(512) */

#define WS_TAG  0                     /* int[3][256]                        */
#define WS_GRP  768                   /* float[3][NG*64]                    */
#define WS_HP   13056                 /* float[3][64]                       */
#define WS_GH   13248                 /* float[3][1536]                     */
#define WS_GI   17856                 /* float[40*1536]                     */

__device__ __forceinline__ int ld_tag(const int* p) {
  return __hip_atomic_load(p, __ATOMIC_RELAXED, __HIP_MEMORY_SCOPE_AGENT);
}
__device__ __forceinline__ float ld_af(const float* p) {
  return __hip_atomic_load(p, __ATOMIC_RELAXED, __HIP_MEMORY_SCOPE_AGENT);
}
__device__ __forceinline__ void st_af(float* p, float v) {
  __hip_atomic_store(p, v, __ATOMIC_RELAXED, __HIP_MEMORY_SCOPE_AGENT);
}
__device__ __forceinline__ void st_tag_rel(int* p, int v) {
  __hip_atomic_store(p, v, __ATOMIC_RELEASE, __HIP_MEMORY_SCOPE_AGENT);
}
__device__ __forceinline__ int ld_lds_acq(int* p) {
  return __hip_atomic_load(p, __ATOMIC_ACQUIRE, __HIP_MEMORY_SCOPE_WORKGROUP);
}
__device__ __forceinline__ void st_lds_rel(int* p, int v) {
  __hip_atomic_store(p, v, __ATOMIC_RELEASE, __HIP_MEMORY_SCOPE_WORKGROUP);
}
__device__ __forceinline__ void lds_add_rel(int* p) {
  __hip_atomic_fetch_add(p, 1, __ATOMIC_RELEASE, __HIP_MEMORY_SCOPE_WORKGROUP);
}

__device__ __forceinline__ float wred(float s) {
#pragma unroll
  for (int o = 32; o > 0; o >>= 1) s += __shfl_xor(s, o, 64);
  return s;
}
__device__ __forceinline__ float dot8(float4 a0, float4 a1, float4 b0,
                                      float4 b1) {
  return a0.x * b0.x + a0.y * b0.y + a0.z * b0.z + a0.w * b0.w +
         a1.x * b1.x + a1.y * b1.y + a1.z * b1.z + a1.w * b1.w;
}
__device__ __forceinline__ float wdot512(const float* __restrict__ a,
                                         const float* __restrict__ b) {
  const int l = threadIdx.x & 63;
  const float4 a0 = ((const float4*)a)[l];
  const float4 a1 = ((const float4*)a)[l + 64];
  const float4 b0 = ((const float4*)b)[l];
  const float4 b1 = ((const float4*)b)[l + 64];
  return wred(dot8(a0, a1, b0, b1));
}

__global__ void __launch_bounds__(NT, 4) dec_main(
    const float* __restrict__ enc, const float* __restrict__ hidden,
    const float* __restrict__ embed, const float* __restrict__ w_ih,
    const float* __restrict__ w_hh, const float* __restrict__ b_ih,
    const float* __restrict__ b_hh, const float* __restrict__ w_out,
    const float* __restrict__ b_out, float* __restrict__ o,
    float* __restrict__ ws) {
  const int b = blockIdx.x, tid = threadIdx.x;
  const int wave = tid >> 6, lane = tid & 63;
  const int g = b & (NG - 1);
  const int r0 = b * ROWS;
  int* wsi = (int*)ws;

  __shared__ __align__(16) float h_lds[512];
  __shared__ float pw_lds[NW * 64];   // dot-phase fold partials
  __shared__ float pwg_lds[8 * 64];   // gather-wave partial colsums
  __shared__ float sc_lds[1];
  __shared__ int go_lds;              // t+1 when step-t tags all observed
  __shared__ int gcnt;                // monotonic gather counter
  __shared__ int bf_lds;              // (t<<6)|best

  // ----------------- prologue -----------------
  if (tid < 512) h_lds[tid] = hidden[tid];
  if (tid == 0) { go_lds = 0; gcnt = 0; bf_lds = -1; }

  // gi_all[v][j] = W_ih[j].embed[v] + b_ih[j]  (240 dots per block)
  for (int u = wave; u < 240; u += NW) {
    const int gl = b * 240 + u;
    const int v = gl / 1536, j = gl - v * 1536;
    const float d = wdot512(w_ih + (size_t)j * 512, embed + (size_t)v * 512);
    if (lane == 0) st_af(&ws[WS_GI + (size_t)v * 1536 + j], d + b_ih[j]);
  }
  // gh(h0): 6 rows (waves 0-5) directly into gh slot 2
  if (wave < 6) {
    const int j = b * 6 + wave;
    const float d = wdot512(w_hh + (size_t)j * 512, hidden);
    if (lane == 0) st_af(&ws[WS_GH + 2 * 1536 + j], d + b_hh[j]);
  }
  // zero group accumulators of slots 0 and 1 (blocks 0..63 own region b)
  if (b < NG) {
    if (wave == 6 && lane < 48) st_af(&ws[WS_GRP + 0 * 4096 + b * 64 + lane], 0.0f);
    if (wave == 7 && lane < 48) st_af(&ws[WS_GRP + 1 * 4096 + b * 64 + lane], 0.0f);
  }
  __syncthreads();  // every wave drains vmcnt before s_barrier
  if (tid == 0) st_tag_rel(wsi + WS_TAG + 2 * 256 + b, 0);

  // --- register-resident K rows and M columns ---
  const float* k0p = enc + (size_t)(r0 + 2 * wave) * 1024;
  const float4 k0a = ((const float4*)k0p)[lane];
  const float4 k0b = ((const float4*)k0p)[lane + 64];
  const float4 k1a = ((const float4*)(k0p + 1024))[lane];
  const float4 k1b = ((const float4*)(k0p + 1024))[lane + 64];
  float Mr0 = (lane == 40) ? 1.0f : 0.0f, Mr1 = Mr0;
  {
    const float* v0p = k0p + 512;
    const float4 va0 = ((const float4*)v0p)[lane];
    const float4 va1 = ((const float4*)v0p)[lane + 64];
    const float4 vb0 = ((const float4*)(v0p + 1024))[lane];
    const float4 vb1 = ((const float4*)(v0p + 1024))[lane + 64];
    for (int v = 0; v < NV; ++v) {
      const float* wp = w_out + (size_t)v * 1024;
      const float4 w0 = ((const float4*)wp)[lane];
      const float4 w1 = ((const float4*)wp)[lane + 64];
      const float sa = wred(dot8(va0, va1, w0, w1));
      const float sb = wred(dot8(vb0, vb1, w0, w1));
      if (lane == v) { Mr0 = sa; Mr1 = sb; }
    }
  }
  // aux row regs: waves 1-6 -> W_hh row; wave 7 -> W_out hp row (blocks 1..40)
  float4 xa0 = {0, 0, 0, 0}, xa1 = {0, 0, 0, 0};
  float xb = 0.0f;
  if (wave >= 1 && wave <= 6) {
    const int j = b * 6 + (wave - 1);
    const float* wp = w_hh + (size_t)j * 512;
    xa0 = ((const float4*)wp)[lane];
    xa1 = ((const float4*)wp)[lane + 64];
    xb = b_hh[j];
  } else if (wave == 7 && b >= 1 && b <= NV) {
    const float* wp = w_out + (size_t)(b - 1) * 1024 + 512;
    xa0 = ((const float4*)wp)[lane];
    xa1 = ((const float4*)wp)[lane + 64];
    xb = b_out[b - 1];
  }

  // ----------------- main loop -----------------
  int eos_reg = -1;            // block0/wave0/lane0 only
  float p0 = 0.0f, p1 = 0.0f;  // this wave's unnormalized attention weights
  float* attn = o + (size_t)MAXLEN * NV + 1;

  for (int t = 0; t <= MAXLEN; ++t) {
    const int s2 = (t + 2) % 3;  // slot holding step-(t-1) publications

    if (wave == 0) {
      // ---- single poller: all 256 tags, 4 independent loads per lane ----
      {
        const int* tp = wsi + WS_TAG + s2 * 256 + lane;
        bool ok = false;
        for (;;) {
          if (!ok) {
            const int a0 = ld_tag(tp);
            const int a1 = ld_tag(tp + 64);
            const int a2 = ld_tag(tp + 128);
            const int a3 = ld_tag(tp + 192);
            ok = ((a0 == t) & (a1 == t) & (a2 == t) & (a3 == t)) != 0;
          }
          if (__ballot(!ok) == 0ull) break;
          __builtin_amdgcn_s_sleep(1);
        }
      }
      if (lane == 0) st_lds_rel(&go_lds, t + 1);  // everyone may start loads
      if (t > 0) {
        // hp load (independent, issued before gather chain)
        const float hp =
            (lane < NV) ? ld_af(ws + WS_HP + s2 * 64 + lane) : 0.0f;
        // gather regions 0..7
        const float* rbl = ws + WS_GRP + s2 * 4096 + lane;
        float c0 = 0, c1 = 0, c2 = 0, c3 = 0;
        c0 = ld_af(rbl + 0 * 64); c1 = ld_af(rbl + 1 * 64);
        c2 = ld_af(rbl + 2 * 64); c3 = ld_af(rbl + 3 * 64);
        c0 += ld_af(rbl + 4 * 64); c1 += ld_af(rbl + 5 * 64);
        c2 += ld_af(rbl + 6 * 64); c3 += ld_af(rbl + 7 * 64);
        pwg_lds[lane] = (c0 + c1) + (c2 + c3);
        if (lane == 0) lds_add_rel(&gcnt);
        while (ld_lds_acq(&gcnt) < 8 * t) __builtin_amdgcn_s_sleep(1);
        float cs8 = 0.0f;
#pragma unroll
        for (int w2 = 0; w2 < 8; ++w2) cs8 += pwg_lds[w2 * 64 + lane];
        const float S = __shfl(cs8, 40, 64);
        const float ov = cs8 * (1.0f / S) + hp;
        unsigned long long key = 0ull;
        if (lane < NV) {
          unsigned u = __float_as_uint(ov);
          u = (u & 0x80000000u) ? ~u : (u | 0x80000000u);
          key = ((unsigned long long)u << 32) | (unsigned)(~lane);
        }
#pragma unroll
        for (int mm = 32; mm > 0; mm >>= 1) {
          const unsigned long long k2 = __shfl_xor(key, mm, 64);
          if (k2 > key) key = k2;
        }
        const int best = (int)(~(unsigned)key);
        if (lane == 0) sc_lds[0] = S;
        if (b == 0 && lane < NV) o[(size_t)(t - 1) * NV + lane] = ov;
        if (b == 0 && lane == 0) {
          if (best == EOS_IDX && eos_reg < 0) eos_reg = t - 1;
          if (t == MAXLEN)
            o[(size_t)MAXLEN * NV] =
                (eos_reg < 0) ? (float)MAXLEN : (float)eos_reg;
        }
        if (lane == 0) st_lds_rel(&bf_lds, (t << 6) | best);
      } else if (lane == 0) {
        st_lds_rel(&bf_lds, EOS_IDX);  // (0<<6)|EOS
      }
    } else if (wave < 8) {
      // ---- gather waves 1-7: wait LDS go, load 8 regions each ----
      while (ld_lds_acq(&go_lds) < t + 1) __builtin_amdgcn_s_sleep(1);
      if (t > 0) {
        const float* rbl = ws + WS_GRP + s2 * 4096 + (wave * 8) * 64 + lane;
        float c0 = 0, c1 = 0, c2 = 0, c3 = 0;
        c0 = ld_af(rbl + 0 * 64); c1 = ld_af(rbl + 1 * 64);
        c2 = ld_af(rbl + 2 * 64); c3 = ld_af(rbl + 3 * 64);
        c0 += ld_af(rbl + 4 * 64); c1 += ld_af(rbl + 5 * 64);
        c2 += ld_af(rbl + 6 * 64); c3 += ld_af(rbl + 7 * 64);
        pwg_lds[wave * 64 + lane] = (c0 + c1) + (c2 + c3);
        if (lane == 0) lds_add_rel(&gcnt);
      }
    } else if (t < MAXLEN) {
      // ---- GRU waves 8-15: wait go, load gh (coalesced), wait best ----
      const int j = tid - 512;
      while (ld_lds_acq(&go_lds) < t + 1) __builtin_amdgcn_s_sleep(1);
      const float* ghs = ws + WS_GH + s2 * 1536;
      const float ghr = ld_af(ghs + j);
      const float ghz = ld_af(ghs + j + 512);
      const float ghn = ld_af(ghs + j + 1024);
      int bf;
      while (((bf = ld_lds_acq(&bf_lds)) >> 6) < t) __builtin_amdgcn_s_sleep(1);
      const float* gi = ws + WS_GI + (size_t)(bf & 63) * 1536;
      const float gir = gi[j], giz = gi[j + 512], gin = gi[j + 1024];
      const float r = 1.0f / (1.0f + expf(-(gir + ghr)));
      const float z = 1.0f / (1.0f + expf(-(giz + ghz)));
      const float n = tanhf(gin + r * ghn);
      h_lds[j] = (1.0f - z) * n + z * h_lds[j];
    }
    __syncthreads();  // barrier A: h_t, sc_lds ready

    if (t > 0 && lane < 2)  // previous step's normalized attention weights
      attn[(size_t)(t - 1) * TENC + r0 + 2 * wave + lane] =
          (lane ? p1 : p0) * (1.0f / sc_lds[0]);
    if (t == MAXLEN) break;

    // ---- dots: 2 K-dots + fold partial (regs); aux row (regs) ----
    {
      const float4 hh0 = ((const float4*)h_lds)[lane];
      const float4 hh1 = ((const float4*)h_lds)[lane + 64];
      const float d0 = wred(dot8(k0a, k0b, hh0, hh1));
      const float d1 = wred(dot8(k1a, k1b, hh0, hh1));
      p0 = expf(d0 * SCALE);
      p1 = expf(d1 * SCALE);
      pw_lds[wave * 64 + lane] = p0 * Mr0 + p1 * Mr1;
      if (wave >= 1 && wave <= 6) {  // gh_t row for step t+1
        const float d = wred(dot8(xa0, xa1, hh0, hh1));
        if (lane == 0) st_af(&ws[WS_GH + (t % 3) * 1536 + b * 6 + (wave - 1)],
                             d + xb);
      } else if (wave == 7 && b >= 1 && b <= NV) {  // hp row
        const float d = wred(dot8(xa0, xa1, hh0, hh1));
        if (lane == 0) st_af(&ws[WS_HP + (t % 3) * 64 + (b - 1)], d + xb);
      } else if (wave == 15 && b < NG && lane < 48) {
        // zero group region b of slot (t+1)%3 (provably consumed)
        st_af(&ws[WS_GRP + ((t + 1) % 3) * 4096 + b * 64 + lane], 0.0f);
      }
    }
    __syncthreads();  // barrier C: pw complete, ALL waves' stores drained

    // ---- wave0: reduce, atomic publish, release tag ----
    if (wave == 0) {
      float red = 0.0f;
#pragma unroll
      for (int w2 = 0; w2 < NW; ++w2) red += pw_lds[w2 * 64 + lane];
      if (lane <= 40)
        atomicAdd(&ws[WS_GRP + (t % 3) * 4096 + g * 64 + lane], red);
      if (lane == 0)
        st_tag_rel(wsi + WS_TAG + (t % 3) * 256 + b, t + 1);
    }
  }
}

extern "C" void kernel_launch(void* const* d_in, const int* in_sizes, int n_in,
                              void* d_out, int out_size, void* d_ws,
                              size_t ws_size, hipStream_t stream) {
  const float* enc    = (const float*)d_in[0];
  const float* hidden = (const float*)d_in[1];
  const float* embed  = (const float*)d_in[2];
  const float* w_ih   = (const float*)d_in[3];
  const float* w_hh   = (const float*)d_in[4];
  const float* b_ih   = (const float*)d_in[5];
  const float* b_hh   = (const float*)d_in[6];
  const float* w_out  = (const float*)d_in[7];
  const float* b_out  = (const float*)d_in[8];
  float* out = (float*)d_out;
  float* ws  = (float*)d_ws;

  dec_main<<<dim3(NB), dim3(NT), 0, stream>>>(enc, hidden, embed, w_ih, w_hh,
                                              b_ih, b_hh, w_out, b_out, out,
                                              ws);
}